// Round 5
// baseline (543.970 us; speedup 1.0000x reference)
//
#include <hip/hip_runtime.h>

// EmbeddingBagCollection: T=8 tables, B=4096 bags, L=50 lookups, V=100000, D=128.
// out[b, t*D + d] = sum_l tables[t, indices[t,b,l], d]
//
// R5 = R4 with the compile fix: __builtin_nontemporal_store needs a native
// clang vector type, not HIP_vector_type<float,4>.
//
// R4 theory: gather path looked MSHR×latency-bound (1.56 TB/s effective,
// insensitive to per-wave pipeline depth). Lever: reduce per-miss latency by
// keeping ONE 51.2MB table hot in the 256MB L3 at a time. Grid = 512 blocks
// (all co-resident on 256 CUs), each block owns 8 bags (b fixed) and loops
// t=0..7 -> whole GPU sweeps tables in lockstep; rows reused ~2.05x hit L3
// instead of HBM.
//  - one 32-lane group per bag: lane owns float4 (32 x 16B = 512B row)
//  - scalar table base per (block,t); u32 row offset idx<<9 | lane<<4
//  - CHUNK=10 index prefetch keeps 10 independent row loads in flight
//  - nontemporal output stores: don't evict table rows from L2/L3

#define T_ 8
#define B_ 4096
#define L_ 50
#define V_ 100000
#define D_ 128
#define CHUNK 10

typedef float v4f __attribute__((ext_vector_type(4)));

__global__ __launch_bounds__(256) void EmbeddingBagCollection_56959856279962_kernel(
    const int* __restrict__ indices,   // [T, B, L] int32
    const float* __restrict__ tables,  // [T, V, D] f32
    float* __restrict__ out)           // [B, T*D] f32
{
    const int group = threadIdx.x >> 5;               // bag within block
    const int lane  = threadIdx.x & 31;               // float4 within row
    const int b     = (blockIdx.x << 3) + group;      // bag id, fixed per thread

    for (int t = 0; t < T_; ++t) {                    // tables swept in lockstep
        const int* __restrict__ idxp = indices + ((size_t)t * B_ + b) * L_;
        const float* __restrict__ tbl = tables + (size_t)t * (V_ * D_);

        v4f acc = (v4f){0.f, 0.f, 0.f, 0.f};

        int cur[CHUNK], nxt[CHUNK];
#pragma unroll
        for (int j = 0; j < CHUNK; ++j) cur[j] = idxp[j];

#pragma unroll
        for (int l = 0; l < L_; l += CHUNK) {
            if (l + CHUNK < L_) {
#pragma unroll
                for (int j = 0; j < CHUNK; ++j) nxt[j] = idxp[l + CHUNK + j];
            }
#pragma unroll
            for (int j = 0; j < CHUNK; ++j) {
                // row byte offset: idx * D * 4 = idx*512 -> <<9 (max 51.2MB, u32 ok)
                const unsigned off = ((unsigned)cur[j] << 9) | ((unsigned)lane << 4);
                const v4f v = *(const v4f*)((const char*)tbl + off);
                acc += v;
            }
#pragma unroll
            for (int j = 0; j < CHUNK; ++j) cur[j] = nxt[j];
        }

        v4f* __restrict__ op =
            (v4f*)(out + (size_t)b * (T_ * D_) + (size_t)t * D_);
        __builtin_nontemporal_store(acc, op + lane);
    }
}

extern "C" void kernel_launch(void* const* d_in, const int* in_sizes, int n_in,
                              void* d_out, int out_size, void* d_ws, size_t ws_size,
                              hipStream_t stream) {
    const int*   indices = (const int*)d_in[0];   // [T,B,L] int32
    const float* tables  = (const float*)d_in[1]; // [T,V,D] f32
    float*       out     = (float*)d_out;         // [B, T*D] f32

    const int grid = B_ / 8;                      // 512 blocks, 8 bags each,
                                                  // all co-resident -> lockstep t
    EmbeddingBagCollection_56959856279962_kernel<<<grid, 256, 0, stream>>>(
        indices, tables, out);
}